// Round 5
// baseline (978.541 us; speedup 1.0000x reference)
//
#include <hip/hip_runtime.h>
#include <hip/hip_bf16.h>

typedef __bf16 bf16;
typedef __attribute__((ext_vector_type(8))) __bf16 bf16x8;
typedef __attribute__((ext_vector_type(4))) __bf16 bf16x4;
typedef __attribute__((ext_vector_type(4))) float f32x4;

#define MFMA16(a, b, c) __builtin_amdgcn_mfma_f32_16x16x32_bf16((a), (b), (c), 0, 0, 0)

constexpr int Bb = 4, Nn = 2047, Cc = 1024, Hh = 16, Dd = 64;
constexpr int M_ROWS = Bb * Nn;      // 8188
constexpr int NPAD = 2048;           // padded kv stride for V^T
constexpr float SCALE = 0.125f;      // D^-0.5
constexpr float NEG_BIG = -1e30f;    // finite sentinel (no inf anywhere)
constexpr float DEFER_THR = 8.0f;    // defer-max rescale threshold (T13)

template <bool V> struct BC { static constexpr bool value = V; };

__device__ inline bf16x8 bzero8() {
    bf16x8 v;
    for (int i = 0; i < 8; ++i) v[i] = (bf16)0.0f;
    return v;
}
__device__ inline bf16x8 bones8() {
    bf16x8 v;
    for (int i = 0; i < 8; ++i) v[i] = (bf16)1.0f;
    return v;
}
__device__ inline f32x4 fzero4() {
    f32x4 v = {0.f, 0.f, 0.f, 0.f};
    return v;
}

// async global->LDS DMA, 16 B per lane; LDS dest = wave-uniform base + lane*16
__device__ __forceinline__ void async_copy16(const void* g, void* l) {
    __builtin_amdgcn_global_load_lds(
        (const __attribute__((address_space(1))) unsigned int*)g,
        (__attribute__((address_space(3))) unsigned int*)l, 16, 0, 0);
}

// ---------------------------------------------------------------------------
// fp32 -> bf16 convert for x, qkv_w, proj_w (one launch)
// ---------------------------------------------------------------------------
__global__ __launch_bounds__(256) void cvt3_kernel(
    const float* __restrict__ a, bf16* __restrict__ oa, int na8,
    const float* __restrict__ b, bf16* __restrict__ ob, int nb8,
    const float* __restrict__ c, bf16* __restrict__ oc, int nc8) {
    int i = blockIdx.x * blockDim.x + threadIdx.x;
    const float* src;
    bf16* dst;
    int j = i;
    if (j < na8) {
        src = a; dst = oa;
    } else {
        j -= na8;
        if (j < nb8) {
            src = b; dst = ob;
        } else {
            j -= nb8;
            if (j >= nc8) return;
            src = c; dst = oc;
        }
    }
    float4 x0 = ((const float4*)src)[2 * (size_t)j];
    float4 x1 = ((const float4*)src)[2 * (size_t)j + 1];
    bf16x8 v;
    v[0] = (bf16)x0.x; v[1] = (bf16)x0.y; v[2] = (bf16)x0.z; v[3] = (bf16)x0.w;
    v[4] = (bf16)x1.x; v[5] = (bf16)x1.y; v[6] = (bf16)x1.z; v[7] = (bf16)x1.w;
    *(bf16x8*)(dst + 8 * (size_t)j) = v;
}

// ---------------------------------------------------------------------------
// V (B,H,N,D) -> V^T (B,H,D,NPAD), zero-padded at n >= Nn. Runs once.
// ---------------------------------------------------------------------------
__global__ __launch_bounds__(256) void transpose_v_kernel(
    const bf16* __restrict__ vd, bf16* __restrict__ vtd) {
    __shared__ bf16 t[64 * 72];
    const int bh = blockIdx.x, nt = blockIdx.y;
    const int tid = threadIdx.x;
    const bf16* src = vd + (size_t)bh * Nn * Dd;
    bf16* dst = vtd + (size_t)bh * Dd * NPAD;
    int c = tid;
    for (int it = 0; it < 2; ++it, c += 256) {
        int row = c >> 3, d8 = (c & 7) * 8;
        int gn = nt * 64 + row;
        bf16x8 v = bzero8();
        if (gn < Nn) v = *(const bf16x8*)(src + (size_t)gn * Dd + d8);
        *(bf16x8*)(t + row * 72 + d8) = v;
    }
    __syncthreads();
    c = tid;
    for (int it = 0; it < 2; ++it, c += 256) {
        int d = c >> 3, j8 = (c & 7) * 8;
        bf16x8 v;
        for (int k = 0; k < 8; ++k) v[k] = t[(j8 + k) * 72 + d];
        *(bf16x8*)(dst + (size_t)d * NPAD + nt * 64 + j8) = v;
    }
}

// ---------------------------------------------------------------------------
// GEMM (m97 structure): out(M x NOUT) = A(M x 1024) @ W(NOUT x 1024)^T
// NOTE (r4 post-mortem): explicit double-buffer + XCD chunk decode measured
// NEUTRAL (634 -> 642 us) -- consistent with learn_hip m99/m100 (the
// vmcnt(0)+barrier drain is structural). Keep the simple 2-barrier form.
// ---------------------------------------------------------------------------
template <int NOUT, int MODE>
__global__ __launch_bounds__(256, 2) void gemm_kernel(
    const bf16* __restrict__ A, const bf16* __restrict__ W,
    const float* __restrict__ pb, bf16* __restrict__ qd, bf16* __restrict__ kd,
    bf16* __restrict__ vd, float* __restrict__ outd) {
    constexpr int Kdim = 1024;
    __shared__ bf16 As[128 * 32];
    __shared__ bf16 Bs[128 * 32];

    const int tid = threadIdx.x;
    const int wave = tid >> 6, lane = tid & 63;
    const int quad = lane >> 4, l16 = lane & 15;
    const int m0 = blockIdx.y * 128;
    const int n0 = blockIdx.x * 128;
    const int wm = (wave >> 1) * 64, wn = (wave & 1) * 64;

    const int dma_r = lane >> 2;          // row within 16-row group
    const int dma_k = (lane & 3) * 8;     // elem offset within row

    f32x4 acc[4][4];
    for (int mi = 0; mi < 4; ++mi)
        for (int ni = 0; ni < 4; ++ni) acc[mi][ni] = fzero4();

    for (int kb = 0; kb < Kdim; kb += 32) {
        __syncthreads();
        for (int i = 0; i < 2; ++i) {
            int g = wave * 2 + i;                 // 16-row group 0..7
            int row = g * 16 + dma_r;
            int gm = m0 + row;
            if (gm > M_ROWS - 1) gm = M_ROWS - 1;
            async_copy16(A + (size_t)gm * Kdim + kb + dma_k, As + g * 16 * 32);
        }
        for (int i = 0; i < 2; ++i) {
            int g = wave * 2 + i;
            int row = g * 16 + dma_r;
            async_copy16(W + (size_t)(n0 + row) * Kdim + kb + dma_k,
                         Bs + g * 16 * 32);
        }
        __syncthreads();

        bf16x8 af[4], bfr[4];
        for (int mi = 0; mi < 4; ++mi)
            af[mi] = *(const bf16x8*)(As + (wm + mi * 16 + l16) * 32 + quad * 8);
        for (int ni = 0; ni < 4; ++ni)
            bfr[ni] = *(const bf16x8*)(Bs + (wn + ni * 16 + l16) * 32 + quad * 8);
        for (int mi = 0; mi < 4; ++mi)
            for (int ni = 0; ni < 4; ++ni)
                acc[mi][ni] = MFMA16(af[mi], bfr[ni], acc[mi][ni]);
    }

    for (int mi = 0; mi < 4; ++mi) {
        for (int r = 0; r < 4; ++r) {
            int gm = m0 + wm + mi * 16 + quad * 4 + r;
            if (gm >= M_ROWS) continue;
            int bb = gm / Nn;
            int nn = gm - bb * Nn;
            for (int ni = 0; ni < 4; ++ni) {
                int gn = n0 + wn + ni * 16 + l16;
                float val = acc[mi][ni][r];
                if (MODE == 0) {
                    int which = gn >> 10;
                    int hh = (gn >> 6) & 15;
                    int dd = gn & 63;
                    size_t dst = ((size_t)(bb * Hh + hh) * Nn + nn) * Dd + dd;
                    if (which == 0)
                        qd[dst] = (bf16)(val * SCALE);
                    else if (which == 1)
                        kd[dst] = (bf16)val;
                    else
                        vd[dst] = (bf16)val;
                } else {
                    outd[(size_t)gm * NOUT + gn] = val + pb[gn];
                }
            }
        }
    }
}

// ---------------------------------------------------------------------------
// Flash attention, S^T formulation -- BARRIER-FREE fragment-direct version.
// Theory (r5): the staged version was LDS-pipe/lockstep-bound -- all 4 waves
// read the SAME Ks/VTs rows (4x redundant b128 LDS traffic) and 2 barriers
// per tile coupled every wave to the slowest load. K (8 KB) and V^T (8 KB)
// tiles are L1/L2-resident, so staging them was pure overhead (guide common-
// mistake #7). Now each wave loads its K / V^T MFMA fragments directly from
// global into registers, prefetched one tile ahead; only Ps (wave-private)
// stays in LDS; the kv-loop has NO __syncthreads at all.
// XCD-aware decode kept (bias fetched ~once per XCD, r1: FETCH 647->220 MB).
// Bias feeds the S-MFMA C-operand directly from prefetch regs.
// No launch_bounds min-waves: (256,5) previously forced spills (r2 disaster).
// ---------------------------------------------------------------------------
__global__ __launch_bounds__(256) void attn_kernel(
    const bf16* __restrict__ q, const bf16* __restrict__ kk,
    const bf16* __restrict__ vt, const float* __restrict__ bias,
    bf16* __restrict__ out) {
    __shared__ bf16 Ps[64 * 72];    // [q][kv], wave-private rows

    const int tid = threadIdx.x;
    const int wave = tid >> 6, lane = tid & 63;
    const int quad = lane >> 4, l16 = lane & 15;

    // XCD-aware decode: xcd c owns h in {2c, 2c+1}; the 4 batch-blocks of one
    // (qt,h) run adjacently on the same XCD.
    const int flat = blockIdx.x;
    const int xcd = flat & 7;
    const int sidx = flat >> 3;              // 0..255
    const int pair = xcd * 64 + (sidx >> 2); // 0..511 = (qt,h)
    const int b = sidx & 3;
    const int qt = pair & 31;
    const int h = pair >> 5;

    const int q0 = qt * 64;
    const int wq0 = wave * 16;

    const size_t head_off = (size_t)(b * Hh + h) * Nn * Dd;
    const bf16* qh = q + head_off;
    const bf16* kh = kk + head_off;
    const bf16* vth = vt + (size_t)(b * Hh + h) * Dd * NPAD;

    // per-lane fixed bias row: this lane's q-column is q0+wq0+l16 (clamped)
    int gq_lane = q0 + wq0 + l16;
    if (gq_lane > Nn - 1) gq_lane = Nn - 1;
    const float* brow = bias + ((size_t)h * Nn + gq_lane) * Nn;

    // Q fragments direct from global (loop-invariant)
    const bf16* qrow = qh + (size_t)gq_lane * Dd;
    const bf16x8 bq0 = *(const bf16x8*)(qrow + quad * 8);
    const bf16x8 bq1 = *(const bf16x8*)(qrow + 32 + quad * 8);
    const bf16x8 ones = bones8();

    // ---- per-wave fragment prefetch registers (tile t)
    bf16x8 ak[4][2];   // K A-frags: row kv0+mi*16+l16, k-half hf
    bf16x8 av[4][2];   // V^T B-frags: row d=nd*16+l16, kv-half hf
    f32x4 bp[4];       // bias, C-layout (reg r <-> kv quad*4+r)

    auto issue_k = [&](int kvn) {
        // NOTE: row kvn+mi*16+l16 may reach 2047 (== Nn) on the last tile;
        // that read lands in the adjacent workspace buffer (in-bounds) and
        // the resulting sT element is masked to NEG_BIG before use.
#pragma unroll
        for (int mi = 0; mi < 4; ++mi)
#pragma unroll
            for (int hf = 0; hf < 2; ++hf)
                ak[mi][hf] = *(const bf16x8*)(
                    kh + (size_t)(kvn + mi * 16 + l16) * Dd + hf * 32 + quad * 8);
    };
    auto issue_v = [&](int kvn) {
#pragma unroll
        for (int nd = 0; nd < 4; ++nd)
#pragma unroll
            for (int hf = 0; hf < 2; ++hf)
                av[nd][hf] = *(const bf16x8*)(
                    vth + (size_t)(nd * 16 + l16) * NPAD + kvn + hf * 32 + quad * 8);
    };
    auto issue_bias = [&](int tn) {
        const int kvn = tn * 64;
        if (tn < 31) {  // interior: r=0..3 are consecutive columns -> f32x4
#pragma unroll
            for (int mi = 0; mi < 4; ++mi)
                bp[mi] = *(const f32x4*)(brow + kvn + mi * 16 + quad * 4);
        } else {        // boundary tile: scalar bounded loads (no overread)
#pragma unroll
            for (int mi = 0; mi < 4; ++mi) {
                int base = kvn + mi * 16 + quad * 4;
                f32x4 f;
                f[0] = (base + 0 < Nn) ? brow[base + 0] : 0.f;
                f[1] = (base + 1 < Nn) ? brow[base + 1] : 0.f;
                f[2] = (base + 2 < Nn) ? brow[base + 2] : 0.f;
                f[3] = (base + 3 < Nn) ? brow[base + 3] : 0.f;
                bp[mi] = f;
            }
        }
    };

    issue_k(0);
    issue_v(0);
    issue_bias(0);

    f32x4 acc_o[4];     // O in C/D layout: row q=quad*4+r, col d=nd*16+l16
    for (int nd = 0; nd < 4; ++nd) acc_o[nd] = fzero4();
    f32x4 acc_l = fzero4();  // row-sums l, same row layout
    float m_run = NEG_BIG;   // per-lane: reference max for q-column l16

    auto tile = [&](int t, auto lastc) {
        constexpr bool LAST = decltype(lastc)::value;
        const int kv0 = t * 64;

        // S^T = K.Q^T + bias (bias pre-loaded into the accumulator).
        // Consumes ak + bp -> their registers are free for t+1 right after.
        f32x4 sT[4];
        __builtin_amdgcn_s_setprio(1);
#pragma unroll
        for (int mi = 0; mi < 4; ++mi) {
            sT[mi] = MFMA16(ak[mi][0], bq0, bp[mi]);
            sT[mi] = MFMA16(ak[mi][1], bq1, sT[mi]);
        }
        __builtin_amdgcn_s_setprio(0);

        // prefetch next tile's K + bias; latency hides under softmax + PV
        if (!LAST) {
            issue_k(kv0 + 64);
            issue_bias(t + 1);
        }

        // OOB masking only on the peeled last tile
        if (LAST) {
#pragma unroll
            for (int mi = 0; mi < 4; ++mi)
#pragma unroll
                for (int r = 0; r < 4; ++r) {
                    int kv = kv0 + mi * 16 + quad * 4 + r;
                    if (kv >= Nn) sT[mi][r] = NEG_BIG;
                }
        }

        // online softmax for q-column l16: in-lane max + xor16/32
        float mx = sT[0][0];
#pragma unroll
        for (int mi = 0; mi < 4; ++mi)
#pragma unroll
            for (int r = 0; r < 4; ++r) mx = fmaxf(mx, sT[mi][r]);
        mx = fmaxf(mx, __shfl_xor(mx, 16));
        mx = fmaxf(mx, __shfl_xor(mx, 32));
        float mnew = fmaxf(m_run, mx);

        // defer-max (T13): skip rescale while max growth <= THR on all cols
        float m_old = m_run;
        bool need = !__all(mnew - m_run <= DEFER_THR);
        if (need) m_run = mnew;

        // P = exp(s - m_run), packed b64 stores into A-layout [q][kv]
        // (Ps rows are wave-private: no barrier, lgkmcnt only)
#pragma unroll
        for (int mi = 0; mi < 4; ++mi) {
            bf16x4 pv;
#pragma unroll
            for (int r = 0; r < 4; ++r)
                pv[r] = (bf16)__expf(sT[mi][r] - m_run);
            *(bf16x4*)(Ps + (wq0 + l16) * 72 + mi * 16 + quad * 4) = pv;
        }

        if (need) {
            float alpha_col = __expf(m_old - m_run);
            // alpha to row layout (q = quad*4+r lives in lane quad*4+r)
            float ar[4];
#pragma unroll
            for (int r = 0; r < 4; ++r) ar[r] = __shfl(alpha_col, quad * 4 + r);
#pragma unroll
            for (int nd = 0; nd < 4; ++nd)
#pragma unroll
                for (int r = 0; r < 4; ++r) acc_o[nd][r] *= ar[r];
#pragma unroll
            for (int r = 0; r < 4; ++r) acc_l[r] *= ar[r];
        }

        // O += P.V ; l += P.1   (consumes av -> free for t+1 after)
        bf16x8 ap0 = *(const bf16x8*)(Ps + (wq0 + l16) * 72 + quad * 8);
        bf16x8 ap1 = *(const bf16x8*)(Ps + (wq0 + l16) * 72 + 32 + quad * 8);
        __builtin_amdgcn_s_setprio(1);
#pragma unroll
        for (int nd = 0; nd < 4; ++nd) {
            acc_o[nd] = MFMA16(ap0, av[nd][0], acc_o[nd]);
            acc_o[nd] = MFMA16(ap1, av[nd][1], acc_o[nd]);
        }
        acc_l = MFMA16(ap0, ones, acc_l);
        acc_l = MFMA16(ap1, ones, acc_l);
        __builtin_amdgcn_s_setprio(0);

        // prefetch next tile's V; latency hides under next S + softmax
        if (!LAST) issue_v(kv0 + 64);
    };

    for (int t = 0; t < 31; ++t) tile(t, BC<false>{});
    tile(31, BC<true>{});

    // write attn_out (B, N, C) bf16; l is in matching row layout
    for (int nd = 0; nd < 4; ++nd) {
        for (int r = 0; r < 4; ++r) {
            int gq = q0 + wq0 + quad * 4 + r;
            if (gq >= Nn) continue;
            float val = acc_o[nd][r] / acc_l[r];
            out[((size_t)b * Nn + gq) * Cc + h * 64 + nd * 16 + l16] = (bf16)val;
        }
    }
}

extern "C" void kernel_launch(void* const* d_in, const int* in_sizes, int n_in,
                              void* d_out, int out_size, void* d_ws,
                              size_t ws_size, hipStream_t stream) {
    const float* x = (const float*)d_in[0];
    const float* qkv_w = (const float*)d_in[1];
    const float* proj_w = (const float*)d_in[2];
    const float* proj_b = (const float*)d_in[3];
    const float* bias = (const float*)d_in[4];
    float* out = (float*)d_out;

    const size_t per = (size_t)Bb * Hh * Nn * Dd;     // 8,384,512
    const size_t nx = (size_t)M_ROWS * Cc;            // 8,384,512
    const size_t nqw = (size_t)3 * Cc * Cc;           // 3,145,728
    const size_t npw = (size_t)Cc * Cc;               // 1,048,576

    // ws layout (bf16 elems): [qkvwb][projwb][qd][kd][vd][ao][R: xb then vtd]
    bf16* qkvwb = (bf16*)d_ws;
    bf16* projwb = qkvwb + nqw;
    bf16* qd = projwb + npw;
    bf16* kd = qd + per;
    bf16* vd = kd + per;
    bf16* ao = vd + per;
    bf16* xb = ao + nx;        // region R: x (bf16) until QKV GEMM done...
    bf16* vtd = ao + nx;       // ...then reused for V^T (16.8 MB)

    // 0) convert x, qkv_w, proj_w to bf16
    {
        int na8 = (int)(nx / 8), nb8 = (int)(nqw / 8), nc8 = (int)(npw / 8);
        int tot = na8 + nb8 + nc8;
        cvt3_kernel<<<(tot + 255) / 256, 256, 0, stream>>>(
            x, xb, na8, qkv_w, qkvwb, nb8, proj_w, projwb, nc8);
    }
    // 1) QKV projection -> q (scaled), k, v in (B,H,N,D) bf16
    gemm_kernel<3072, 0><<<dim3(24, 64), 256, 0, stream>>>(
        xb, qkvwb, nullptr, qd, kd, vd, nullptr);
    // 2) V -> V^T (B,H,D,NPAD), zero-padded (overwrites xb region; xb is dead)
    transpose_v_kernel<<<dim3(64, 32), 256, 0, stream>>>(vd, vtd);
    // 3) flash attention, 1D grid + XCD-aware (qt,h,b) decode for bias reuse
    attn_kernel<<<dim3(2048), 256, 0, stream>>>(qd, kd, vtd, bias, ao);
    // 4) output projection + bias -> fp32 out
    gemm_kernel<1024, 1><<<dim3(8, 64), 256, 0, stream>>>(
        ao, projwb, proj_b, nullptr, nullptr, nullptr, out);
}

// Round 7
// 630.078 us; speedup vs baseline: 1.5530x; 1.5530x over previous
//
#include <hip/hip_runtime.h>
#include <hip/hip_bf16.h>

typedef __bf16 bf16;
typedef __attribute__((ext_vector_type(8))) __bf16 bf16x8;
typedef __attribute__((ext_vector_type(4))) __bf16 bf16x4;
typedef __attribute__((ext_vector_type(4))) float f32x4;

#define MFMA16(a, b, c) __builtin_amdgcn_mfma_f32_16x16x32_bf16((a), (b), (c), 0, 0, 0)

constexpr int Bb = 4, Nn = 2047, Cc = 1024, Hh = 16, Dd = 64;
constexpr int M_ROWS = Bb * Nn;      // 8188
constexpr int NPAD = 2048;           // padded kv stride for V^T
constexpr float SCALE = 0.125f;      // D^-0.5
constexpr float NEG_BIG = -1e30f;    // finite sentinel (no inf anywhere)
constexpr float DEFER_THR = 8.0f;    // defer-max rescale threshold (T13)

template <bool V> struct BC { static constexpr bool value = V; };

__device__ inline bf16x8 bzero8() {
    bf16x8 v;
    for (int i = 0; i < 8; ++i) v[i] = (bf16)0.0f;
    return v;
}
__device__ inline bf16x8 bones8() {
    bf16x8 v;
    for (int i = 0; i < 8; ++i) v[i] = (bf16)1.0f;
    return v;
}
__device__ inline f32x4 fzero4() {
    f32x4 v = {0.f, 0.f, 0.f, 0.f};
    return v;
}

// async global->LDS DMA, 16 B per lane; LDS dest = wave-uniform base + lane*16
__device__ __forceinline__ void async_copy16(const void* g, void* l) {
    __builtin_amdgcn_global_load_lds(
        (const __attribute__((address_space(1))) unsigned int*)g,
        (__attribute__((address_space(3))) unsigned int*)l, 16, 0, 0);
}

// ---------------------------------------------------------------------------
// fp32 -> bf16 convert for x, qkv_w, proj_w (one launch)
// ---------------------------------------------------------------------------
__global__ __launch_bounds__(256) void cvt3_kernel(
    const float* __restrict__ a, bf16* __restrict__ oa, int na8,
    const float* __restrict__ b, bf16* __restrict__ ob, int nb8,
    const float* __restrict__ c, bf16* __restrict__ oc, int nc8) {
    int i = blockIdx.x * blockDim.x + threadIdx.x;
    const float* src;
    bf16* dst;
    int j = i;
    if (j < na8) {
        src = a; dst = oa;
    } else {
        j -= na8;
        if (j < nb8) {
            src = b; dst = ob;
        } else {
            j -= nb8;
            if (j >= nc8) return;
            src = c; dst = oc;
        }
    }
    float4 x0 = ((const float4*)src)[2 * (size_t)j];
    float4 x1 = ((const float4*)src)[2 * (size_t)j + 1];
    bf16x8 v;
    v[0] = (bf16)x0.x; v[1] = (bf16)x0.y; v[2] = (bf16)x0.z; v[3] = (bf16)x0.w;
    v[4] = (bf16)x1.x; v[5] = (bf16)x1.y; v[6] = (bf16)x1.z; v[7] = (bf16)x1.w;
    *(bf16x8*)(dst + 8 * (size_t)j) = v;
}

// ---------------------------------------------------------------------------
// V (B,H,N,D) -> V^T (B,H,D,NPAD), zero-padded at n >= Nn. Runs once.
// ---------------------------------------------------------------------------
__global__ __launch_bounds__(256) void transpose_v_kernel(
    const bf16* __restrict__ vd, bf16* __restrict__ vtd) {
    __shared__ bf16 t[64 * 72];
    const int bh = blockIdx.x, nt = blockIdx.y;
    const int tid = threadIdx.x;
    const bf16* src = vd + (size_t)bh * Nn * Dd;
    bf16* dst = vtd + (size_t)bh * Dd * NPAD;
    int c = tid;
    for (int it = 0; it < 2; ++it, c += 256) {
        int row = c >> 3, d8 = (c & 7) * 8;
        int gn = nt * 64 + row;
        bf16x8 v = bzero8();
        if (gn < Nn) v = *(const bf16x8*)(src + (size_t)gn * Dd + d8);
        *(bf16x8*)(t + row * 72 + d8) = v;
    }
    __syncthreads();
    c = tid;
    for (int it = 0; it < 2; ++it, c += 256) {
        int d = c >> 3, j8 = (c & 7) * 8;
        bf16x8 v;
        for (int k = 0; k < 8; ++k) v[k] = t[(j8 + k) * 72 + d];
        *(bf16x8*)(dst + (size_t)d * NPAD + nt * 64 + j8) = v;
    }
}

// ---------------------------------------------------------------------------
// GEMM (m97 structure): out(M x NOUT) = A(M x 1024) @ W(NOUT x 1024)^T
// r4 post-mortem: explicit double-buffer + XCD chunking measured NEUTRAL
// (learn_hip m99/m100: barrier drain is structural). Keep 2-barrier form.
// ---------------------------------------------------------------------------
template <int NOUT, int MODE>
__global__ __launch_bounds__(256, 2) void gemm_kernel(
    const bf16* __restrict__ A, const bf16* __restrict__ W,
    const float* __restrict__ pb, bf16* __restrict__ qd, bf16* __restrict__ kd,
    bf16* __restrict__ vd, float* __restrict__ outd) {
    constexpr int Kdim = 1024;
    __shared__ bf16 As[128 * 32];
    __shared__ bf16 Bs[128 * 32];

    const int tid = threadIdx.x;
    const int wave = tid >> 6, lane = tid & 63;
    const int quad = lane >> 4, l16 = lane & 15;
    const int m0 = blockIdx.y * 128;
    const int n0 = blockIdx.x * 128;
    const int wm = (wave >> 1) * 64, wn = (wave & 1) * 64;

    const int dma_r = lane >> 2;          // row within 16-row group
    const int dma_k = (lane & 3) * 8;     // elem offset within row

    f32x4 acc[4][4];
    for (int mi = 0; mi < 4; ++mi)
        for (int ni = 0; ni < 4; ++ni) acc[mi][ni] = fzero4();

    for (int kb = 0; kb < Kdim; kb += 32) {
        __syncthreads();
        for (int i = 0; i < 2; ++i) {
            int g = wave * 2 + i;                 // 16-row group 0..7
            int row = g * 16 + dma_r;
            int gm = m0 + row;
            if (gm > M_ROWS - 1) gm = M_ROWS - 1;
            async_copy16(A + (size_t)gm * Kdim + kb + dma_k, As + g * 16 * 32);
        }
        for (int i = 0; i < 2; ++i) {
            int g = wave * 2 + i;
            int row = g * 16 + dma_r;
            async_copy16(W + (size_t)(n0 + row) * Kdim + kb + dma_k,
                         Bs + g * 16 * 32);
        }
        __syncthreads();

        bf16x8 af[4], bfr[4];
        for (int mi = 0; mi < 4; ++mi)
            af[mi] = *(const bf16x8*)(As + (wm + mi * 16 + l16) * 32 + quad * 8);
        for (int ni = 0; ni < 4; ++ni)
            bfr[ni] = *(const bf16x8*)(Bs + (wn + ni * 16 + l16) * 32 + quad * 8);
        for (int mi = 0; mi < 4; ++mi)
            for (int ni = 0; ni < 4; ++ni)
                acc[mi][ni] = MFMA16(af[mi], bfr[ni], acc[mi][ni]);
    }

    for (int mi = 0; mi < 4; ++mi) {
        for (int r = 0; r < 4; ++r) {
            int gm = m0 + wm + mi * 16 + quad * 4 + r;
            if (gm >= M_ROWS) continue;
            int bb = gm / Nn;
            int nn = gm - bb * Nn;
            for (int ni = 0; ni < 4; ++ni) {
                int gn = n0 + wn + ni * 16 + l16;
                float val = acc[mi][ni][r];
                if (MODE == 0) {
                    int which = gn >> 10;
                    int hh = (gn >> 6) & 15;
                    int dd = gn & 63;
                    size_t dst = ((size_t)(bb * Hh + hh) * Nn + nn) * Dd + dd;
                    if (which == 0)
                        qd[dst] = (bf16)(val * SCALE);
                    else if (which == 1)
                        kd[dst] = (bf16)val;
                    else
                        vd[dst] = (bf16)val;
                } else {
                    outd[(size_t)gm * NOUT + gn] = val + pb[gn];
                }
            }
        }
    }
}

// ---------------------------------------------------------------------------
// Flash attention, S^T formulation, O^T epilogue. Staged LDS K/V (coalesced
// global->reg->LDS, r5 lesson: fragment-direct global gathers are 16-line
// uncoalesced and 2.6x WORSE). O^T = V^T . P^T -- the S^T output IS P^T
// already, so PV's B-operand is built from sT via 16 in-register shuffles;
// the Ps LDS buffer, its write->wait->read chain, the alpha re-layout
// shuffles, and the scalar epilogue all disappear. LDS 27.6->18.4KB.
// launch_bounds(256,4) = 128-VGPR CAP only (r2 lesson: (256,5)'s 102-cap
// forced spills, WRITE_SIZE 36->305MB. Never cap below natural usage.)
// ---------------------------------------------------------------------------
__global__ __launch_bounds__(256, 4) void attn_kernel(
    const bf16* __restrict__ q, const bf16* __restrict__ kk,
    const bf16* __restrict__ vt, const float* __restrict__ bias,
    bf16* __restrict__ out) {
    __shared__ bf16 Ks[64 * 72];
    __shared__ bf16 VTs[64 * 72];   // [d][kv]

    const int tid = threadIdx.x;
    const int wave = tid >> 6, lane = tid & 63;
    const int quad = lane >> 4, l16 = lane & 15;

    // XCD-aware decode: xcd c owns h in {2c, 2c+1}; the 4 batch-blocks of one
    // (qt,h) run adjacently on the same XCD (r1: FETCH 647->220 MB).
    const int flat = blockIdx.x;
    const int xcd = flat & 7;
    const int sidx = flat >> 3;              // 0..255
    const int pair = xcd * 64 + (sidx >> 2); // 0..511 = (qt,h)
    const int b = sidx & 3;
    const int qt = pair & 31;
    const int h = pair >> 5;

    const int q0 = qt * 64;
    const int wq0 = wave * 16;

    const size_t head_off = (size_t)(b * Hh + h) * Nn * Dd;
    const bf16* qh = q + head_off;
    const bf16* kh = kk + head_off;
    const bf16* vth = vt + (size_t)(b * Hh + h) * Dd * NPAD;

    // per-lane fixed bias row: this lane's q-column is q0+wq0+l16 (clamped)
    int gq_lane = q0 + wq0 + l16;
    if (gq_lane > Nn - 1) gq_lane = Nn - 1;
    const float* brow = bias + ((size_t)h * Nn + gq_lane) * Nn;

    // staging lane geometry (rows srow and srow+32, 8 bf16 each)
    const int srow = tid >> 3;
    const int sd8 = (tid & 7) * 8;

    // Q fragments direct from global (loop-invariant)
    const bf16* qrow = qh + (size_t)gq_lane * Dd;
    const bf16x8 bq0 = *(const bf16x8*)(qrow + quad * 8);
    const bf16x8 bq1 = *(const bf16x8*)(qrow + 32 + quad * 8);
    const bf16x8 ones = bones8();

    // ---- prefetch registers (tile t's K/V + bias arrive by the top barrier)
    bf16x8 pk0, pk1, pv0, pv1;
    float4 bp[4];

    auto issue_kv_fast = [&](int kvn) {   // all rows in-bounds (kvn+63 < Nn)
        int g0 = kvn + srow, g1 = g0 + 32;
        pk0 = *(const bf16x8*)(kh + (size_t)g0 * Dd + sd8);
        pk1 = *(const bf16x8*)(kh + (size_t)g1 * Dd + sd8);
        pv0 = *(const bf16x8*)(vth + (size_t)srow * NPAD + kvn + sd8);
        pv1 = *(const bf16x8*)(vth + (size_t)(srow + 32) * NPAD + kvn + sd8);
    };
    auto issue_kv_last = [&](int kvn) {   // kvn = 1984: clamp K rows
        int g0 = kvn + srow, g1 = g0 + 32;
        pk0 = bzero8();
        pk1 = bzero8();
        if (g0 < Nn) pk0 = *(const bf16x8*)(kh + (size_t)g0 * Dd + sd8);
        if (g1 < Nn) pk1 = *(const bf16x8*)(kh + (size_t)g1 * Dd + sd8);
        pv0 = *(const bf16x8*)(vth + (size_t)srow * NPAD + kvn + sd8);
        pv1 = *(const bf16x8*)(vth + (size_t)(srow + 32) * NPAD + kvn + sd8);
    };
    auto issue_bias = [&](int tn) {
        const int kvn = tn * 64;
        if (tn < 31) {  // interior: r=0..3 are consecutive columns -> float4
#pragma unroll
            for (int mi = 0; mi < 4; ++mi)
                bp[mi] = *(const float4*)(brow + kvn + mi * 16 + quad * 4);
        } else {        // boundary tile: scalar bounded loads (no overread)
#pragma unroll
            for (int mi = 0; mi < 4; ++mi) {
                int base = kvn + mi * 16 + quad * 4;
                float4 f;
                f.x = (base + 0 < Nn) ? brow[base + 0] : 0.f;
                f.y = (base + 1 < Nn) ? brow[base + 1] : 0.f;
                f.z = (base + 2 < Nn) ? brow[base + 2] : 0.f;
                f.w = (base + 3 < Nn) ? brow[base + 3] : 0.f;
                bp[mi] = f;
            }
        }
    };

    issue_kv_fast(0);
    issue_bias(0);

    f32x4 acc_oT[4];    // O^T in C/D layout: row d=nd*16+quad*4+r, col q=l16
    for (int nd = 0; nd < 4; ++nd) acc_oT[nd] = fzero4();
    f32x4 acc_l = fzero4();  // all rows equal: l for q-column l16
    float m_run = NEG_BIG;   // per-lane: reference max for q-column l16

    // shuffle geometry for P^T redistribution (C-layout -> B-operand layout)
    const int la = ((quad & 1) * 2) * 16 + l16;  // source lane a (same l16)
    const int lb = la + 16;                      // source lane b
    const bool hiSel = (quad >> 1) != 0;         // selects mi within pair

    auto tile = [&](int t, auto lastc) {
        constexpr bool LAST = decltype(lastc)::value;
        const int kv0 = t * 64;
        __syncthreads();  // prior iter LDS reads done; prefetch regs landed

        // write staged K / V^T registers to LDS
        *(bf16x8*)(Ks + srow * 72 + sd8) = pk0;
        *(bf16x8*)(Ks + (srow + 32) * 72 + sd8) = pk1;
        *(bf16x8*)(VTs + srow * 72 + sd8) = pv0;
        *(bf16x8*)(VTs + (srow + 32) * 72 + sd8) = pv1;

        // capture this tile's bias as MFMA C-init (reg r <-> kv quad*4+r)
        f32x4 cin[4];
#pragma unroll
        for (int mi = 0; mi < 4; ++mi) {
            cin[mi][0] = bp[mi].x; cin[mi][1] = bp[mi].y;
            cin[mi][2] = bp[mi].z; cin[mi][3] = bp[mi].w;
        }

        __syncthreads();  // staged LDS visible to all waves

        // issue next tile's loads NOW: they fly across the whole compute
        // phase and drain exactly at the next top __syncthreads
        if (!LAST) {
            if (t + 1 < 31) issue_kv_fast(kv0 + 64);
            else issue_kv_last(kv0 + 64);
            issue_bias(t + 1);
        }

        // S^T = K.Q^T + bias (bias pre-loaded into the accumulator)
        // sT[mi] holds P^T pre-exp: row kv = kv0+mi*16+quad*4+r, col q = l16
        f32x4 sT[4];
        __builtin_amdgcn_s_setprio(1);
#pragma unroll
        for (int mi = 0; mi < 4; ++mi) {
            bf16x8 ak0 = *(const bf16x8*)(Ks + (mi * 16 + l16) * 72 + quad * 8);
            bf16x8 ak1 = *(const bf16x8*)(Ks + (mi * 16 + l16) * 72 + 32 + quad * 8);
            sT[mi] = MFMA16(ak0, bq0, cin[mi]);
            sT[mi] = MFMA16(ak1, bq1, sT[mi]);
        }
        __builtin_amdgcn_s_setprio(0);

        // OOB masking only on the peeled last tile
        if (LAST) {
#pragma unroll
            for (int mi = 0; mi < 4; ++mi)
#pragma unroll
                for (int r = 0; r < 4; ++r) {
                    int kv = kv0 + mi * 16 + quad * 4 + r;
                    if (kv >= Nn) sT[mi][r] = NEG_BIG;
                }
        }

        // online softmax for q-column l16: in-lane max + xor16/32
        float mx = sT[0][0];
#pragma unroll
        for (int mi = 0; mi < 4; ++mi)
#pragma unroll
            for (int r = 0; r < 4; ++r) mx = fmaxf(mx, sT[mi][r]);
        mx = fmaxf(mx, __shfl_xor(mx, 16));
        mx = fmaxf(mx, __shfl_xor(mx, 32));
        float mnew = fmaxf(m_run, mx);

        // defer-max (T13): skip rescale while max growth <= THR on all cols
        float m_old = m_run;
        bool need = !__all(mnew - m_run <= DEFER_THR);
        if (need) m_run = mnew;

        // P = exp(s - m_run), packed bf16x4 per mi (kept in registers)
        unsigned long long pv64[4];
#pragma unroll
        for (int mi = 0; mi < 4; ++mi) {
            union { bf16x4 v; unsigned long long u; } pk;
#pragma unroll
            for (int r = 0; r < 4; ++r)
                pk.v[r] = (bf16)__expf(sT[mi][r] - m_run);
            pv64[mi] = pk.u;
        }

        if (need) {
            float alpha = __expf(m_old - m_run);  // this lane's own q-column
#pragma unroll
            for (int nd = 0; nd < 4; ++nd)
#pragma unroll
                for (int r = 0; r < 4; ++r) acc_oT[nd][r] *= alpha;
#pragma unroll
            for (int r = 0; r < 4; ++r) acc_l[r] *= alpha;
        }

        // Build PV B-operands: B2[hf] lane(quad,l16) needs
        // P^T[kv=hf*32+quad*8+e][l16]: e0-3 from lane la, e4-7 from lane lb,
        // mi = 2*hf + (quad>>1). Pure cross-lane, no LDS buffer.
        bf16x8 B2[2];
#pragma unroll
        for (int hf = 0; hf < 2; ++hf) {
            unsigned long long lo0 = __shfl(pv64[2 * hf + 0], la);
            unsigned long long lo1 = __shfl(pv64[2 * hf + 1], la);
            unsigned long long hi0 = __shfl(pv64[2 * hf + 0], lb);
            unsigned long long hi1 = __shfl(pv64[2 * hf + 1], lb);
            union { bf16x8 v; unsigned long long u[2]; } cat;
            cat.u[0] = hiSel ? lo1 : lo0;
            cat.u[1] = hiSel ? hi1 : hi0;
            B2[hf] = cat.v;
        }

        // O^T += V^T . P^T ; l += 1 . P^T (A = V^T rows d, B = P^T)
        __builtin_amdgcn_s_setprio(1);
#pragma unroll
        for (int nd = 0; nd < 4; ++nd) {
            bf16x8 av0 = *(const bf16x8*)(VTs + (nd * 16 + l16) * 72 + quad * 8);
            bf16x8 av1 = *(const bf16x8*)(VTs + (nd * 16 + l16) * 72 + 32 + quad * 8);
            acc_oT[nd] = MFMA16(av0, B2[0], acc_oT[nd]);
            acc_oT[nd] = MFMA16(av1, B2[1], acc_oT[nd]);
        }
        acc_l = MFMA16(ones, B2[0], acc_l);
        acc_l = MFMA16(ones, B2[1], acc_l);
        __builtin_amdgcn_s_setprio(0);
    };

    for (int t = 0; t < 31; ++t) tile(t, BC<false>{});
    tile(31, BC<true>{});

    // write attn_out (B, N, C) bf16. Lane owns ONE q-row (col l16 of O^T):
    // q = q0+wq0+l16, d = nd*16+quad*4+r -> 4 contiguous bf16 per store.
    if (q0 + wq0 + l16 < Nn) {
        const float linv = 1.0f / acc_l[0];  // all rows of acc_l are equal
        bf16* orow = out + ((size_t)b * Nn + (q0 + wq0 + l16)) * Cc + h * 64;
#pragma unroll
        for (int nd = 0; nd < 4; ++nd) {
            bf16x4 ov;
#pragma unroll
            for (int r = 0; r < 4; ++r)
                ov[r] = (bf16)(acc_oT[nd][r] * linv);
            *(bf16x4*)(orow + nd * 16 + quad * 4) = ov;
        }
    }
}

extern "C" void kernel_launch(void* const* d_in, const int* in_sizes, int n_in,
                              void* d_out, int out_size, void* d_ws,
                              size_t ws_size, hipStream_t stream) {
    const float* x = (const float*)d_in[0];
    const float* qkv_w = (const float*)d_in[1];
    const float* proj_w = (const float*)d_in[2];
    const float* proj_b = (const float*)d_in[3];
    const float* bias = (const float*)d_in[4];
    float* out = (float*)d_out;

    const size_t per = (size_t)Bb * Hh * Nn * Dd;     // 8,384,512
    const size_t nx = (size_t)M_ROWS * Cc;            // 8,384,512
    const size_t nqw = (size_t)3 * Cc * Cc;           // 3,145,728
    const size_t npw = (size_t)Cc * Cc;               // 1,048,576

    // ws layout (bf16 elems): [qkvwb][projwb][qd][kd][vd][ao][R: xb then vtd]
    bf16* qkvwb = (bf16*)d_ws;
    bf16* projwb = qkvwb + nqw;
    bf16* qd = projwb + npw;
    bf16* kd = qd + per;
    bf16* vd = kd + per;
    bf16* ao = vd + per;
    bf16* xb = ao + nx;        // region R: x (bf16) until QKV GEMM done...
    bf16* vtd = ao + nx;       // ...then reused for V^T (16.8 MB)

    // 0) convert x, qkv_w, proj_w to bf16
    {
        int na8 = (int)(nx / 8), nb8 = (int)(nqw / 8), nc8 = (int)(npw / 8);
        int tot = na8 + nb8 + nc8;
        cvt3_kernel<<<(tot + 255) / 256, 256, 0, stream>>>(
            x, xb, na8, qkv_w, qkvwb, nb8, proj_w, projwb, nc8);
    }
    // 1) QKV projection -> q (scaled), k, v in (B,H,N,D) bf16
    gemm_kernel<3072, 0><<<dim3(24, 64), 256, 0, stream>>>(
        xb, qkvwb, nullptr, qd, kd, vd, nullptr);
    // 2) V -> V^T (B,H,D,NPAD), zero-padded (overwrites xb region; xb is dead)
    transpose_v_kernel<<<dim3(64, 32), 256, 0, stream>>>(vd, vtd);
    // 3) flash attention, 1D grid + XCD-aware (qt,h,b) decode for bias reuse
    attn_kernel<<<dim3(2048), 256, 0, stream>>>(qd, kd, vtd, bias, ao);
    // 4) output projection + bias -> fp32 out
    gemm_kernel<1024, 1><<<dim3(8, 64), 256, 0, stream>>>(
        ao, projwb, proj_b, nullptr, nullptr, nullptr, out);
}